// Round 1
// baseline (421.668 us; speedup 1.0000x reference)
//
#include <hip/hip_runtime.h>
#include <stdint.h>
#include <stddef.h>

typedef int i32x4 __attribute__((ext_vector_type(4)));

static constexpr int M = 8192, N = 4096, K = 4096;
static constexpr int BM = 256, BN = 256, BK = 128;  // 256^2 tile, 2 k-half units of 64B
static constexpr int NT = K / BK;                   // 32 K-tiles

// ---------------- preprocessing (unchanged, verified) ----------------

__global__ __launch_bounds__(256) void quant_rows(const float* __restrict__ x,
                                                  int8_t* __restrict__ xq,
                                                  float* __restrict__ scales) {
    const int row = blockIdx.x;
    const int tid = threadIdx.x;
    const float4* xr = (const float4*)(x + (size_t)row * K);  // 1024 float4/row

    float4 v[4];
    float m = 0.f;
#pragma unroll
    for (int k = 0; k < 4; ++k) {
        v[k] = xr[k * 256 + tid];
        m = fmaxf(m, fmaxf(fmaxf(fabsf(v[k].x), fabsf(v[k].y)),
                           fmaxf(fabsf(v[k].z), fabsf(v[k].w))));
    }
#pragma unroll
    for (int off = 32; off; off >>= 1) m = fmaxf(m, __shfl_down(m, off, 64));

    __shared__ float wm[4];
    if ((tid & 63) == 0) wm[tid >> 6] = m;
    __syncthreads();
    const float amax = fmaxf(fmaxf(fmaxf(wm[0], wm[1]), fmaxf(wm[2], wm[3])), 1e-20f);
    const float s = 127.0f / amax;
    if (tid == 0) scales[row] = amax * (1.0f / 127.0f);

    int8_t* xo = xq + (size_t)row * K;
#pragma unroll
    for (int k = 0; k < 4; ++k) {
        int8_t o[4] = {(int8_t)__float2int_rn(v[k].x * s),
                       (int8_t)__float2int_rn(v[k].y * s),
                       (int8_t)__float2int_rn(v[k].z * s),
                       (int8_t)__float2int_rn(v[k].w * s)};
        *(int*)(xo + (k * 256 + tid) * 4) = *(const int*)o;
    }
}

__global__ __launch_bounds__(256) void binarize_w_kernel(const float* __restrict__ w,
                                                         int8_t* __restrict__ wq) {
    const size_t i = (size_t)blockIdx.x * 256 + threadIdx.x;
    float4 a = ((const float4*)w)[i];
    float vv[4] = {a.x, a.y, a.z, a.w};
    int8_t o[4];
#pragma unroll
    for (int j = 0; j < 4; ++j)
        o[j] = (vv[j] > 0.f) ? (int8_t)1 : ((vv[j] < 0.f) ? (int8_t)-1 : (int8_t)0);
    *(int*)(wq + 4 * i) = *(const int*)o;
}

// ---------------- GEMM: 256^2 tile, counted-vmcnt 2-phase/K-tile pipeline ----------------
// C[M,N] = (Xq[M,K] @ Wq[N,K]^T) * scales[row] + bias[col]
// 512 threads = 8 waves (2 rows x 4 cols), per-wave output 128x64.
// LDS: per matrix 2 buffers x 2 k-half units of [256 rows x 64 B] = 64 KB; total 128 KB.
// Unit swizzle: granule (r, c in [0,4)) stored at c ^ (r&3); fragment granule q ^ (r&3)
//   -> ds_read_b128 conflict-free (8 lanes per 16B bank-slot over 8 cycles).
// Schedule per K-tile t (cur = t&1):
//   PhA: read cur k0 frags; stage t+1 k1 -> buf^1; bar; 32 MFMA ks0; vmcnt(8); bar
//   PhB: read cur k1 frags; stage t+2 k0 -> cur ; bar; 32 MFMA ks1; vmcnt(8); bar
// vmcnt(8) leaves exactly the 2 newest unit-groups (8 loads) in flight; a group is
// consumed 3 phase-windows after issue. Tail: vmcnt 8 -> 4 -> 0 (ledger-verified).

__device__ __forceinline__ void async_copy16(const int8_t* g, int8_t* l) {
    __builtin_amdgcn_global_load_lds(
        (const __attribute__((address_space(1))) void*)g,
        (__attribute__((address_space(3))) void*)l,
        16, 0, 0);
}

#define FENCE() asm volatile("" ::: "memory")
#define BAR() do { FENCE(); __builtin_amdgcn_s_barrier(); FENCE(); } while (0)
#define WAITVM(NN) asm volatile("s_waitcnt vmcnt(" #NN ")" ::: "memory")

__global__ __launch_bounds__(512, 2) void gemm_i8(const int8_t* __restrict__ A,   // [M,K]
                                                  const int8_t* __restrict__ B,   // [N,K]
                                                  const float* __restrict__ bias,
                                                  const float* __restrict__ scales,
                                                  float* __restrict__ C) {        // [M,N]
    __shared__ __align__(16) int8_t As[2][2][BM * 64];  // 64 KB
    __shared__ __align__(16) int8_t Bs[2][2][BN * 64];  // 64 KB

    const int tid  = threadIdx.x;
    const int lane = tid & 63;
    const int wave = tid >> 6;
    const int wr = wave >> 2;       // 0..1  (row half of tile)
    const int wc = wave & 3;        // 0..3  (col quarter)
    const int q  = lane >> 4;       // k-chunk within 64-wide k-step
    const int lr = lane & 15;

    // XCD-aware bijective swizzle: 512 blocks, 8 XCDs, 64 blocks/chunk; bn fast within
    // chunk so 16 blocks share each 1 MB A panel in one XCD's L2.
    const int wg  = blockIdx.x;
    const int swz = (wg & 7) * 64 + (wg >> 3);
    const int m0  = (swz >> 4) * BM;   // 32 m-tiles
    const int n0  = (swz & 15) * BN;   // 16 n-tiles

    i32x4 acc[8][4];
#pragma unroll
    for (int mi = 0; mi < 8; ++mi)
#pragma unroll
        for (int ni = 0; ni < 4; ++ni) acc[mi][ni] = (i32x4)0;

    // fragment LDS byte offsets within a 16 KB unit
    int aoff[8], boff[4];
#pragma unroll
    for (int mi = 0; mi < 8; ++mi) {
        const int r = wr * 128 + mi * 16 + lr;
        aoff[mi] = r * 64 + ((q ^ (r & 3)) * 16);
    }
#pragma unroll
    for (int ni = 0; ni < 4; ++ni) {
        const int r = wc * 64 + ni * 16 + lr;
        boff[ni] = r * 64 + ((q ^ (r & 3)) * 16);
    }

    // staging: unit = 1024 granules of 16B; slot s -> row r=s>>2, lds-granule c=s&3,
    // source granule c ^ (r&3) (involution). LDS dest linear (wave base + lane*16).
    const int s0 = tid, s1 = tid + 512;
    const int8_t* sA0 = A + (size_t)(m0 + (s0 >> 2)) * K + (((s0 & 3) ^ ((s0 >> 2) & 3)) * 16);
    const int8_t* sA1 = A + (size_t)(m0 + (s1 >> 2)) * K + (((s1 & 3) ^ ((s1 >> 2) & 3)) * 16);
    const int8_t* sB0 = B + (size_t)(n0 + (s0 >> 2)) * K + (((s0 & 3) ^ ((s0 >> 2) & 3)) * 16);
    const int8_t* sB1 = B + (size_t)(n0 + (s1 >> 2)) * K + (((s1 & 3) ^ ((s1 >> 2) & 3)) * 16);

#define STAGE(buf, kh, kt) do {                                    \
        const int _ko = (kt) * BK + (kh) * 64;                     \
        async_copy16(sA0 + _ko, &As[buf][kh][s0 * 16]);            \
        async_copy16(sA1 + _ko, &As[buf][kh][s1 * 16]);            \
        async_copy16(sB0 + _ko, &Bs[buf][kh][s0 * 16]);            \
        async_copy16(sB1 + _ko, &Bs[buf][kh][s1 * 16]);            \
    } while (0)

    // prologue: t0 k0, t0 k1, t1 k0 issued (12 loads); wait t0 k0; 8 stay in flight
    STAGE(0, 0, 0);
    STAGE(0, 1, 0);
    STAGE(1, 0, 1);
    WAITVM(8);
    BAR();

#pragma unroll 2
    for (int t = 0; t < NT; ++t) {
        const int cur = t & 1;
        const int nxt = cur ^ 1;

        // ---- Phase A: ks = 0 ----
        {
            const int8_t* Au = &As[cur][0][0];
            const int8_t* Bu = &Bs[cur][0][0];
            i32x4 af[8], bf[4];
#pragma unroll
            for (int mi = 0; mi < 8; ++mi) af[mi] = *(const i32x4*)(Au + aoff[mi]);
#pragma unroll
            for (int ni = 0; ni < 4; ++ni) bf[ni] = *(const i32x4*)(Bu + boff[ni]);
            if (t + 1 < NT) STAGE(nxt, 1, t + 1);   // consumed at PhB(t+1)
            BAR();
            __builtin_amdgcn_s_setprio(1);
#pragma unroll
            for (int mi = 0; mi < 8; ++mi)
#pragma unroll
                for (int ni = 0; ni < 4; ++ni)
                    acc[mi][ni] = __builtin_amdgcn_mfma_i32_16x16x64_i8(
                        af[mi], bf[ni], acc[mi][ni], 0, 0, 0);
            __builtin_amdgcn_s_setprio(0);
            // need t's k1 group complete (staged at PhA(t-1)); newest 2 groups may fly
            if (t < NT - 1) { WAITVM(8); } else { WAITVM(0); }
            BAR();
        }

        // ---- Phase B: ks = 1 ----
        {
            const int8_t* Au = &As[cur][1][0];
            const int8_t* Bu = &Bs[cur][1][0];
            i32x4 af[8], bf[4];
#pragma unroll
            for (int mi = 0; mi < 8; ++mi) af[mi] = *(const i32x4*)(Au + aoff[mi]);
#pragma unroll
            for (int ni = 0; ni < 4; ++ni) bf[ni] = *(const i32x4*)(Bu + boff[ni]);
            if (t + 2 < NT) STAGE(cur, 0, t + 2);   // region last read at PhA(t)
            BAR();
            __builtin_amdgcn_s_setprio(1);
#pragma unroll
            for (int mi = 0; mi < 8; ++mi)
#pragma unroll
                for (int ni = 0; ni < 4; ++ni)
                    acc[mi][ni] = __builtin_amdgcn_mfma_i32_16x16x64_i8(
                        af[mi], bf[ni], acc[mi][ni], 0, 0, 0);
            __builtin_amdgcn_s_setprio(0);
            // need (t+1)'s k0 group complete (staged at PhB(t-1))
            if (t < NT - 2) { WAITVM(8); }
            else if (t == NT - 2) { WAITVM(4); }
            else { WAITVM(0); }
            BAR();
        }
    }
#undef STAGE

    // epilogue: C/D layout col = lane&15, row = (lane>>4)*4 + reg; per-row dequant + bias
    float srow[8][4];
#pragma unroll
    for (int mi = 0; mi < 8; ++mi) {
        const int row0 = m0 + wr * 128 + mi * 16 + q * 4;
#pragma unroll
        for (int i = 0; i < 4; ++i) srow[mi][i] = scales[row0 + i];
    }
#pragma unroll
    for (int ni = 0; ni < 4; ++ni) {
        const int col = n0 + wc * 64 + ni * 16 + lr;
        const float bv = bias[col];
#pragma unroll
        for (int mi = 0; mi < 8; ++mi) {
            const int row0 = m0 + wr * 128 + mi * 16 + q * 4;
#pragma unroll
            for (int i = 0; i < 4; ++i)
                C[(size_t)(row0 + i) * N + col] = (float)acc[mi][ni][i] * srow[mi][i] + bv;
        }
    }
}

// ---------------- launch ----------------

extern "C" void kernel_launch(void* const* d_in, const int* in_sizes, int n_in,
                              void* d_out, int out_size, void* d_ws, size_t ws_size,
                              hipStream_t stream) {
    const float* x    = (const float*)d_in[0];  // [8192, 4096]
    const float* w    = (const float*)d_in[1];  // [4096, 4096]
    const float* bias = (const float*)d_in[2];  // [4096]
    float* out        = (float*)d_out;          // [8192, 4096]

    float* scales = (float*)d_ws;                       // 32 KB (8192 f32)
    int8_t* xq = (int8_t*)d_ws + 32768;                 // 32 MB
    int8_t* wq = xq + (size_t)M * K;                    // 16 MB

    quant_rows<<<M, 256, 0, stream>>>(x, xq, scales);                       // 8192 blocks
    binarize_w_kernel<<<(N * K / 4) / 256, 256, 0, stream>>>(w, wq);        // 16384 blocks

    gemm_i8<<<dim3(512), 512, 0, stream>>>(xq, wq, bias, scales, out);      // 32x16 m,n tiles
}

// Round 2
// 413.864 us; speedup vs baseline: 1.0189x; 1.0189x over previous
//
#include <hip/hip_runtime.h>
#include <stdint.h>
#include <stddef.h>

typedef int i32x4 __attribute__((ext_vector_type(4)));

static constexpr int M = 8192, N = 4096, K = 4096;
static constexpr int BM = 256, BN = 256, BK = 128;  // 256^2 tile, 2 k-half units of 64B
static constexpr int NT = K / BK;                   // 32 K-tiles

// ---------------- preprocessing (unchanged, verified) ----------------

__global__ __launch_bounds__(256) void quant_rows(const float* __restrict__ x,
                                                  int8_t* __restrict__ xq,
                                                  float* __restrict__ scales) {
    const int row = blockIdx.x;
    const int tid = threadIdx.x;
    const float4* xr = (const float4*)(x + (size_t)row * K);  // 1024 float4/row

    float4 v[4];
    float m = 0.f;
#pragma unroll
    for (int k = 0; k < 4; ++k) {
        v[k] = xr[k * 256 + tid];
        m = fmaxf(m, fmaxf(fmaxf(fabsf(v[k].x), fabsf(v[k].y)),
                           fmaxf(fabsf(v[k].z), fabsf(v[k].w))));
    }
#pragma unroll
    for (int off = 32; off; off >>= 1) m = fmaxf(m, __shfl_down(m, off, 64));

    __shared__ float wm[4];
    if ((tid & 63) == 0) wm[tid >> 6] = m;
    __syncthreads();
    const float amax = fmaxf(fmaxf(fmaxf(wm[0], wm[1]), fmaxf(wm[2], wm[3])), 1e-20f);
    const float s = 127.0f / amax;
    if (tid == 0) scales[row] = amax * (1.0f / 127.0f);

    int8_t* xo = xq + (size_t)row * K;
#pragma unroll
    for (int k = 0; k < 4; ++k) {
        int8_t o[4] = {(int8_t)__float2int_rn(v[k].x * s),
                       (int8_t)__float2int_rn(v[k].y * s),
                       (int8_t)__float2int_rn(v[k].z * s),
                       (int8_t)__float2int_rn(v[k].w * s)};
        *(int*)(xo + (k * 256 + tid) * 4) = *(const int*)o;
    }
}

__global__ __launch_bounds__(256) void binarize_w_kernel(const float* __restrict__ w,
                                                         int8_t* __restrict__ wq) {
    const size_t i = (size_t)blockIdx.x * 256 + threadIdx.x;
    float4 a = ((const float4*)w)[i];
    float vv[4] = {a.x, a.y, a.z, a.w};
    int8_t o[4];
#pragma unroll
    for (int j = 0; j < 4; ++j)
        o[j] = (vv[j] > 0.f) ? (int8_t)1 : ((vv[j] < 0.f) ? (int8_t)-1 : (int8_t)0);
    *(int*)(wq + 4 * i) = *(const int*)o;
}

// ---------------- GEMM: 256^2 tile, counted-vmcnt 2-phase/K-tile pipeline ----------------
// C[M,N] = (Xq[M,K] @ Wq[N,K]^T) * scales[row] + bias[col]
// 512 threads = 8 waves (2 rows x 4 cols), per-wave output 128x64.
// LDS: per matrix 2 buffers x 2 k-half units of [256 rows x 64 B] = 64 KB; total 128 KB.
// Unit swizzle f(r) = (r>>1)&3: granule (r, c) stored at c ^ f(r).
//   Read granule q ^ f(r): within a 16-lane group (q fixed, lr=0..15) the bank tuple
//   (lr&1, (lr>>1)&3) covers all 8 (bank-half, granule) combos exactly twice
//   -> 2 lanes per 4-bank group, all 32 banks -> conflict-free ds_read_b128.
//   (Round-1's f(r)=r&3 left lr&1 correlated with the granule -> 4-way, 1.26e7 conflicts.)
// Schedule per K-tile t (cur = t&1):
//   PhA: read cur k0 frags; stage t+1 k1 -> buf^1; bar; 32 MFMA ks0; vmcnt(8); bar
//   PhB: read cur k1 frags; stage t+2 k0 -> cur ; bar; 32 MFMA ks1; vmcnt(8); bar
// vmcnt(8) leaves the 2 newest unit-groups (8 loads) in flight; a group is consumed
// 3 phase-windows after issue. Tail: vmcnt 8 -> 4 -> 0 (ledger-verified, passed R1).

__device__ __forceinline__ void async_copy16(const int8_t* g, int8_t* l) {
    __builtin_amdgcn_global_load_lds(
        (const __attribute__((address_space(1))) void*)g,
        (__attribute__((address_space(3))) void*)l,
        16, 0, 0);
}

#define FENCE() asm volatile("" ::: "memory")
#define BAR() do { FENCE(); __builtin_amdgcn_s_barrier(); FENCE(); } while (0)
#define WAITVM(NN) asm volatile("s_waitcnt vmcnt(" #NN ")" ::: "memory")

__global__ __launch_bounds__(512, 2) void gemm_i8(const int8_t* __restrict__ A,   // [M,K]
                                                  const int8_t* __restrict__ B,   // [N,K]
                                                  const float* __restrict__ bias,
                                                  const float* __restrict__ scales,
                                                  float* __restrict__ C) {        // [M,N]
    __shared__ __align__(16) int8_t As[2][2][BM * 64];  // 64 KB
    __shared__ __align__(16) int8_t Bs[2][2][BN * 64];  // 64 KB

    const int tid  = threadIdx.x;
    const int lane = tid & 63;
    const int wave = tid >> 6;
    const int wr = wave >> 2;       // 0..1  (row half of tile)
    const int wc = wave & 3;        // 0..3  (col quarter)
    const int q  = lane >> 4;       // k-chunk within 64-wide k-step
    const int lr = lane & 15;

    // XCD-aware bijective swizzle: 512 blocks, 8 XCDs, 64 blocks/chunk; bn fast within
    // chunk so 16 blocks share each 1 MB A panel in one XCD's L2.
    const int wg  = blockIdx.x;
    const int swz = (wg & 7) * 64 + (wg >> 3);
    const int m0  = (swz >> 4) * BM;   // 32 m-tiles
    const int n0  = (swz & 15) * BN;   // 16 n-tiles

    i32x4 acc[8][4];
#pragma unroll
    for (int mi = 0; mi < 8; ++mi)
#pragma unroll
        for (int ni = 0; ni < 4; ++ni) acc[mi][ni] = (i32x4)0;

    // fragment LDS byte offsets within a 16 KB unit; granule = q ^ ((r>>1)&3)
    int aoff[8], boff[4];
#pragma unroll
    for (int mi = 0; mi < 8; ++mi) {
        const int r = wr * 128 + mi * 16 + lr;
        aoff[mi] = r * 64 + ((q ^ ((r >> 1) & 3)) * 16);
    }
#pragma unroll
    for (int ni = 0; ni < 4; ++ni) {
        const int r = wc * 64 + ni * 16 + lr;
        boff[ni] = r * 64 + ((q ^ ((r >> 1) & 3)) * 16);
    }

    // staging: unit = 1024 granules of 16B; slot s -> row r=s>>2, lds-granule c=s&3,
    // source granule c ^ ((r>>1)&3) = (s&3) ^ ((s>>3)&3) (involution per row).
    // LDS dest linear (wave base + lane*16) -> staging writes conflict-free.
    const int s0 = tid, s1 = tid + 512;
    const int8_t* sA0 = A + (size_t)(m0 + (s0 >> 2)) * K + (((s0 & 3) ^ ((s0 >> 3) & 3)) * 16);
    const int8_t* sA1 = A + (size_t)(m0 + (s1 >> 2)) * K + (((s1 & 3) ^ ((s1 >> 3) & 3)) * 16);
    const int8_t* sB0 = B + (size_t)(n0 + (s0 >> 2)) * K + (((s0 & 3) ^ ((s0 >> 3) & 3)) * 16);
    const int8_t* sB1 = B + (size_t)(n0 + (s1 >> 2)) * K + (((s1 & 3) ^ ((s1 >> 3) & 3)) * 16);

#define STAGE(buf, kh, kt) do {                                    \
        const int _ko = (kt) * BK + (kh) * 64;                     \
        async_copy16(sA0 + _ko, &As[buf][kh][s0 * 16]);            \
        async_copy16(sA1 + _ko, &As[buf][kh][s1 * 16]);            \
        async_copy16(sB0 + _ko, &Bs[buf][kh][s0 * 16]);            \
        async_copy16(sB1 + _ko, &Bs[buf][kh][s1 * 16]);            \
    } while (0)

    // prologue: t0 k0, t0 k1, t1 k0 issued (12 loads); wait t0 k0; 8 stay in flight
    STAGE(0, 0, 0);
    STAGE(0, 1, 0);
    STAGE(1, 0, 1);
    WAITVM(8);
    BAR();

#pragma unroll 2
    for (int t = 0; t < NT; ++t) {
        const int cur = t & 1;
        const int nxt = cur ^ 1;

        // ---- Phase A: ks = 0 ----
        {
            const int8_t* Au = &As[cur][0][0];
            const int8_t* Bu = &Bs[cur][0][0];
            i32x4 af[8], bf[4];
#pragma unroll
            for (int mi = 0; mi < 8; ++mi) af[mi] = *(const i32x4*)(Au + aoff[mi]);
#pragma unroll
            for (int ni = 0; ni < 4; ++ni) bf[ni] = *(const i32x4*)(Bu + boff[ni]);
            if (t + 1 < NT) STAGE(nxt, 1, t + 1);   // consumed at PhB(t+1)
            BAR();
            __builtin_amdgcn_s_setprio(1);
#pragma unroll
            for (int mi = 0; mi < 8; ++mi)
#pragma unroll
                for (int ni = 0; ni < 4; ++ni)
                    acc[mi][ni] = __builtin_amdgcn_mfma_i32_16x16x64_i8(
                        af[mi], bf[ni], acc[mi][ni], 0, 0, 0);
            __builtin_amdgcn_s_setprio(0);
            // need t's k1 group complete (staged at PhA(t-1)); newest 2 groups may fly
            if (t < NT - 1) { WAITVM(8); } else { WAITVM(0); }
            BAR();
        }

        // ---- Phase B: ks = 1 ----
        {
            const int8_t* Au = &As[cur][1][0];
            const int8_t* Bu = &Bs[cur][1][0];
            i32x4 af[8], bf[4];
#pragma unroll
            for (int mi = 0; mi < 8; ++mi) af[mi] = *(const i32x4*)(Au + aoff[mi]);
#pragma unroll
            for (int ni = 0; ni < 4; ++ni) bf[ni] = *(const i32x4*)(Bu + boff[ni]);
            if (t + 2 < NT) STAGE(cur, 0, t + 2);   // region last read at PhA(t)
            BAR();
            __builtin_amdgcn_s_setprio(1);
#pragma unroll
            for (int mi = 0; mi < 8; ++mi)
#pragma unroll
                for (int ni = 0; ni < 4; ++ni)
                    acc[mi][ni] = __builtin_amdgcn_mfma_i32_16x16x64_i8(
                        af[mi], bf[ni], acc[mi][ni], 0, 0, 0);
            __builtin_amdgcn_s_setprio(0);
            // need (t+1)'s k0 group complete (staged at PhB(t-1))
            if (t < NT - 2) { WAITVM(8); }
            else if (t == NT - 2) { WAITVM(4); }
            else { WAITVM(0); }
            BAR();
        }
    }
#undef STAGE

    // epilogue: C/D layout col = lane&15, row = (lane>>4)*4 + reg; per-row dequant + bias
    float srow[8][4];
#pragma unroll
    for (int mi = 0; mi < 8; ++mi) {
        const int row0 = m0 + wr * 128 + mi * 16 + q * 4;
#pragma unroll
        for (int i = 0; i < 4; ++i) srow[mi][i] = scales[row0 + i];
    }
#pragma unroll
    for (int ni = 0; ni < 4; ++ni) {
        const int col = n0 + wc * 64 + ni * 16 + lr;
        const float bv = bias[col];
#pragma unroll
        for (int mi = 0; mi < 8; ++mi) {
            const int row0 = m0 + wr * 128 + mi * 16 + q * 4;
#pragma unroll
            for (int i = 0; i < 4; ++i)
                C[(size_t)(row0 + i) * N + col] = (float)acc[mi][ni][i] * srow[mi][i] + bv;
        }
    }
}

// ---------------- launch ----------------

extern "C" void kernel_launch(void* const* d_in, const int* in_sizes, int n_in,
                              void* d_out, int out_size, void* d_ws, size_t ws_size,
                              hipStream_t stream) {
    const float* x    = (const float*)d_in[0];  // [8192, 4096]
    const float* w    = (const float*)d_in[1];  // [4096, 4096]
    const float* bias = (const float*)d_in[2];  // [4096]
    float* out        = (float*)d_out;          // [8192, 4096]

    float* scales = (float*)d_ws;                       // 32 KB (8192 f32)
    int8_t* xq = (int8_t*)d_ws + 32768;                 // 32 MB
    int8_t* wq = xq + (size_t)M * K;                    // 16 MB

    quant_rows<<<M, 256, 0, stream>>>(x, xq, scales);                       // 8192 blocks
    binarize_w_kernel<<<(N * K / 4) / 256, 256, 0, stream>>>(w, wq);        // 16384 blocks

    gemm_i8<<<dim3(512), 512, 0, stream>>>(xq, wq, bias, scales, out);      // 32x16 m,n tiles
}

// Round 3
// 402.917 us; speedup vs baseline: 1.0465x; 1.0272x over previous
//
#include <hip/hip_runtime.h>
#include <stdint.h>
#include <stddef.h>

typedef int i32x4 __attribute__((ext_vector_type(4)));

static constexpr int M = 8192, N = 4096, K = 4096;
static constexpr int BM = 256, BN = 256, BK = 128;  // 256^2 tile, 2 k-half units of 64B
static constexpr int NT = K / BK;                   // 32 K-tiles

// ---------------- preprocessing (unchanged, verified) ----------------

__global__ __launch_bounds__(256) void quant_rows(const float* __restrict__ x,
                                                  int8_t* __restrict__ xq,
                                                  float* __restrict__ scales) {
    const int row = blockIdx.x;
    const int tid = threadIdx.x;
    const float4* xr = (const float4*)(x + (size_t)row * K);  // 1024 float4/row

    float4 v[4];
    float m = 0.f;
#pragma unroll
    for (int k = 0; k < 4; ++k) {
        v[k] = xr[k * 256 + tid];
        m = fmaxf(m, fmaxf(fmaxf(fabsf(v[k].x), fabsf(v[k].y)),
                           fmaxf(fabsf(v[k].z), fabsf(v[k].w))));
    }
#pragma unroll
    for (int off = 32; off; off >>= 1) m = fmaxf(m, __shfl_down(m, off, 64));

    __shared__ float wm[4];
    if ((tid & 63) == 0) wm[tid >> 6] = m;
    __syncthreads();
    const float amax = fmaxf(fmaxf(fmaxf(wm[0], wm[1]), fmaxf(wm[2], wm[3])), 1e-20f);
    const float s = 127.0f / amax;
    if (tid == 0) scales[row] = amax * (1.0f / 127.0f);

    int8_t* xo = xq + (size_t)row * K;
#pragma unroll
    for (int k = 0; k < 4; ++k) {
        int8_t o[4] = {(int8_t)__float2int_rn(v[k].x * s),
                       (int8_t)__float2int_rn(v[k].y * s),
                       (int8_t)__float2int_rn(v[k].z * s),
                       (int8_t)__float2int_rn(v[k].w * s)};
        *(int*)(xo + (k * 256 + tid) * 4) = *(const int*)o;
    }
}

__global__ __launch_bounds__(256) void binarize_w_kernel(const float* __restrict__ w,
                                                         int8_t* __restrict__ wq) {
    const size_t i = (size_t)blockIdx.x * 256 + threadIdx.x;
    float4 a = ((const float4*)w)[i];
    float vv[4] = {a.x, a.y, a.z, a.w};
    int8_t o[4];
#pragma unroll
    for (int j = 0; j < 4; ++j)
        o[j] = (vv[j] > 0.f) ? (int8_t)1 : ((vv[j] < 0.f) ? (int8_t)-1 : (int8_t)0);
    *(int*)(wq + 4 * i) = *(const int*)o;
}

// ---------------- GEMM: 256^2 tile, counted-vmcnt 2-phase/K-tile pipeline ----------------
// C[M,N] = (Xq[M,K] @ Wq[N,K]^T) * scales[row] + bias[col]
// 512 threads = 8 waves (2 rows x 4 cols), per-wave output 128x64.
// LDS: per matrix 2 buffers x 2 k-half units of [256 rows x 64 B] = 64 KB; total 128 KB.
// Unit swizzle f(r) = (r>>1)&3 (conflict-free, verified R2: granule stored at c ^ f(r),
//   read at q ^ f(r); 16-lane group covers all 32 banks, 2 lanes/bank = free).
// R3 CHANGE: barriers/waits are now BARE builtins + sched_barrier(0) pins (m201 template).
//   R1/R2 wrapped every barrier/wait in asm("" ::: "memory") — a may-touch-all-memory
//   instruction that forces the waitcnt pass to conservatively drain vmcnt/lgkmcnt,
//   silently turning the counted-vmcnt pipeline into a drain-every-phase (m97) structure.
//   That matches both rounds' 33-40% MfmaUtil at ~3100 cyc/phase (serial read+MFMA).
// Ledger (unchanged, passed twice): steady-state WAITVM(8) leaves the 2 newest 4-load
//   groups in flight; a group is consumed 3 phase-windows after issue. Tail 8 -> 4 -> 0.

__device__ __forceinline__ void async_copy16(const int8_t* g, int8_t* l) {
    __builtin_amdgcn_global_load_lds(
        (const __attribute__((address_space(1))) void*)g,
        (__attribute__((address_space(3))) void*)l,
        16, 0, 0);
}

#define SFENCE() __builtin_amdgcn_sched_barrier(0)
#define BAR() __builtin_amdgcn_s_barrier()
#define WAITVM(NN) asm volatile("s_waitcnt vmcnt(" #NN ")")

__global__ __launch_bounds__(512, 2) void gemm_i8(const int8_t* __restrict__ A,   // [M,K]
                                                  const int8_t* __restrict__ B,   // [N,K]
                                                  const float* __restrict__ bias,
                                                  const float* __restrict__ scales,
                                                  float* __restrict__ C) {        // [M,N]
    __shared__ __align__(16) int8_t As[2][2][BM * 64];  // 64 KB
    __shared__ __align__(16) int8_t Bs[2][2][BN * 64];  // 64 KB

    const int tid  = threadIdx.x;
    const int lane = tid & 63;
    const int wave = tid >> 6;
    const int wr = wave >> 2;       // 0..1  (row half of tile)
    const int wc = wave & 3;        // 0..3  (col quarter)
    const int q  = lane >> 4;       // k-chunk within 64-wide k-step
    const int lr = lane & 15;

    // XCD swizzle, m-fast within chunk: one XCD's 32 concurrent blocks share a single
    // 1 MB B panel (L2-resident) while streaming A panels. (R2's n-fast map cycled
    // 16 B panels through the 4 MB XCD L2 -> thrash.)
    const int wg  = blockIdx.x;
    const int swz = (wg & 7) * 64 + (wg >> 3);
    const int m0  = (swz & 31) * BM;   // 32 m-tiles, fast
    const int n0  = (swz >> 5) * BN;   // 16 n-tiles, slow

    i32x4 acc[8][4];
#pragma unroll
    for (int mi = 0; mi < 8; ++mi)
#pragma unroll
        for (int ni = 0; ni < 4; ++ni) acc[mi][ni] = (i32x4)0;

    // fragment LDS byte offsets within a 16 KB unit; granule = q ^ ((r>>1)&3)
    int aoff[8], boff[4];
#pragma unroll
    for (int mi = 0; mi < 8; ++mi) {
        const int r = wr * 128 + mi * 16 + lr;
        aoff[mi] = r * 64 + ((q ^ ((r >> 1) & 3)) * 16);
    }
#pragma unroll
    for (int ni = 0; ni < 4; ++ni) {
        const int r = wc * 64 + ni * 16 + lr;
        boff[ni] = r * 64 + ((q ^ ((r >> 1) & 3)) * 16);
    }

    // staging: slot s -> row r=s>>2, lds-granule c=s&3, source granule (s&3)^((s>>3)&3).
    // LDS dest linear (wave base + lane*16) -> staging writes conflict-free.
    const int s0 = tid, s1 = tid + 512;
    const int8_t* sA0 = A + (size_t)(m0 + (s0 >> 2)) * K + (((s0 & 3) ^ ((s0 >> 3) & 3)) * 16);
    const int8_t* sA1 = A + (size_t)(m0 + (s1 >> 2)) * K + (((s1 & 3) ^ ((s1 >> 3) & 3)) * 16);
    const int8_t* sB0 = B + (size_t)(n0 + (s0 >> 2)) * K + (((s0 & 3) ^ ((s0 >> 3) & 3)) * 16);
    const int8_t* sB1 = B + (size_t)(n0 + (s1 >> 2)) * K + (((s1 & 3) ^ ((s1 >> 3) & 3)) * 16);

#define STAGE(buf, kh, kt) do {                                    \
        const int _ko = (kt) * BK + (kh) * 64;                     \
        async_copy16(sA0 + _ko, &As[buf][kh][s0 * 16]);            \
        async_copy16(sA1 + _ko, &As[buf][kh][s1 * 16]);            \
        async_copy16(sB0 + _ko, &Bs[buf][kh][s0 * 16]);            \
        async_copy16(sB1 + _ko, &Bs[buf][kh][s1 * 16]);            \
    } while (0)

    // prologue: t0 k0, t0 k1, t1 k0 issued (12 loads); wait first group; 8 stay in flight
    STAGE(0, 0, 0);
    STAGE(0, 1, 0);
    STAGE(1, 0, 1);
    SFENCE();
    WAITVM(8);
    SFENCE();
    BAR();
    SFENCE();

#pragma unroll 2
    for (int t = 0; t < NT; ++t) {
        const int cur = t & 1;
        const int nxt = cur ^ 1;

        // ---- Phase A: ks = 0 ----
        {
            const int8_t* Au = &As[cur][0][0];
            const int8_t* Bu = &Bs[cur][0][0];
            i32x4 af[8], bf[4];
#pragma unroll
            for (int mi = 0; mi < 8; ++mi) af[mi] = *(const i32x4*)(Au + aoff[mi]);
#pragma unroll
            for (int ni = 0; ni < 4; ++ni) bf[ni] = *(const i32x4*)(Bu + boff[ni]);
            if (t + 1 < NT) STAGE(nxt, 1, t + 1);   // consumed at PhB(t+1)
            SFENCE();
            BAR();
            SFENCE();
            __builtin_amdgcn_s_setprio(1);
#pragma unroll
            for (int mi = 0; mi < 8; ++mi)
#pragma unroll
                for (int ni = 0; ni < 4; ++ni)
                    acc[mi][ni] = __builtin_amdgcn_mfma_i32_16x16x64_i8(
                        af[mi], bf[ni], acc[mi][ni], 0, 0, 0);
            __builtin_amdgcn_s_setprio(0);
            SFENCE();
            // need t's k1 group complete (staged at PhA(t-1)); newest 2 groups may fly
            if (t < NT - 1) { WAITVM(8); } else { WAITVM(0); }
            SFENCE();
            BAR();
            SFENCE();
        }

        // ---- Phase B: ks = 1 ----
        {
            const int8_t* Au = &As[cur][1][0];
            const int8_t* Bu = &Bs[cur][1][0];
            i32x4 af[8], bf[4];
#pragma unroll
            for (int mi = 0; mi < 8; ++mi) af[mi] = *(const i32x4*)(Au + aoff[mi]);
#pragma unroll
            for (int ni = 0; ni < 4; ++ni) bf[ni] = *(const i32x4*)(Bu + boff[ni]);
            if (t + 2 < NT) STAGE(cur, 0, t + 2);   // region last read at PhA(t)
            SFENCE();
            BAR();
            SFENCE();
            __builtin_amdgcn_s_setprio(1);
#pragma unroll
            for (int mi = 0; mi < 8; ++mi)
#pragma unroll
                for (int ni = 0; ni < 4; ++ni)
                    acc[mi][ni] = __builtin_amdgcn_mfma_i32_16x16x64_i8(
                        af[mi], bf[ni], acc[mi][ni], 0, 0, 0);
            __builtin_amdgcn_s_setprio(0);
            SFENCE();
            // need (t+1)'s k0 group complete (staged at PhB(t-1))
            if (t < NT - 2) { WAITVM(8); }
            else if (t == NT - 2) { WAITVM(4); }
            else { WAITVM(0); }
            SFENCE();
            BAR();
            SFENCE();
        }
    }
#undef STAGE

    // epilogue: C/D layout col = lane&15, row = (lane>>4)*4 + reg; per-row dequant + bias
    float srow[8][4];
#pragma unroll
    for (int mi = 0; mi < 8; ++mi) {
        const int row0 = m0 + wr * 128 + mi * 16 + q * 4;
#pragma unroll
        for (int i = 0; i < 4; ++i) srow[mi][i] = scales[row0 + i];
    }
#pragma unroll
    for (int ni = 0; ni < 4; ++ni) {
        const int col = n0 + wc * 64 + ni * 16 + lr;
        const float bv = bias[col];
#pragma unroll
        for (int mi = 0; mi < 8; ++mi) {
            const int row0 = m0 + wr * 128 + mi * 16 + q * 4;
#pragma unroll
            for (int i = 0; i < 4; ++i)
                C[(size_t)(row0 + i) * N + col] = (float)acc[mi][ni][i] * srow[mi][i] + bv;
        }
    }
}

// ---------------- launch ----------------

extern "C" void kernel_launch(void* const* d_in, const int* in_sizes, int n_in,
                              void* d_out, int out_size, void* d_ws, size_t ws_size,
                              hipStream_t stream) {
    const float* x    = (const float*)d_in[0];  // [8192, 4096]
    const float* w    = (const float*)d_in[1];  // [4096, 4096]
    const float* bias = (const float*)d_in[2];  // [4096]
    float* out        = (float*)d_out;          // [8192, 4096]

    float* scales = (float*)d_ws;                       // 32 KB (8192 f32)
    int8_t* xq = (int8_t*)d_ws + 32768;                 // 32 MB
    int8_t* wq = xq + (size_t)M * K;                    // 16 MB

    quant_rows<<<M, 256, 0, stream>>>(x, xq, scales);                       // 8192 blocks
    binarize_w_kernel<<<(N * K / 4) / 256, 256, 0, stream>>>(w, wq);        // 16384 blocks

    gemm_i8<<<dim3(512), 512, 0, stream>>>(xq, wq, bias, scales, out);      // 32x16 m,n tiles
}